// Round 2
// baseline (233.886 us; speedup 1.0000x reference)
//
#include <hip/hip_runtime.h>
#include <hip/hip_bf16.h>
#include <math.h>

// inp [B=16, S=4096, D=512] fp32, lengths [16] int32.
// out [B, S, 513] fp32: out[...,0:512] = inp, out[...,512] = pe(b,s).
//
// Key layout fact: 4 output rows = 4*513 = 2052 dwords = 8208 bytes, which is
// divisible by 16 — so tiling the flat output in 4-row groups makes EVERY
// float4 store 16B-aligned (out float4 index == fidx directly, since
// group*2052 + 4j == 4*fidx). Input gather per component: in dword index
// = group*2048 + d - r (d = dword within group, r = row within group),
// scalar dword loads; for fixed component k the lanes stride 16B, but the 4
// component loads cover the same cache lines, so L1 absorbs the overlap.
// pe (cosf) only fires for 4 of 513 float4s per group.

#define PB 16
#define PS 4096
#define PD 512
#define NROWS   (PB * PS)            // 65536
#define NGROUPS (NROWS / 4)          // 16384 four-row groups
#define NF4     (NGROUPS * 513)      // 8,404,992 output float4s
#define PI_F 3.14159265358979323846f

__global__ __launch_bounds__(256) void sinpe_kernel(
    const float* __restrict__ inp,
    const int* __restrict__ lengths,
    float4* __restrict__ out)
{
    const int stride = gridDim.x * blockDim.x;
    for (int fidx = blockIdx.x * blockDim.x + threadIdx.x; fidx < NF4;
         fidx += stride)
    {
        const unsigned g = (unsigned)fidx / 513u;      // 4-row group (magic mul)
        const unsigned j = (unsigned)fidx - g * 513u;  // float4 within group
        const int d0  = 4 * (int)j;                    // dword within group
        const int gin = (int)g * 2048;                 // input dword base

        float vals[4];
        #pragma unroll
        for (int k = 0; k < 4; ++k) {
            const int d = d0 + k;                                  // 0..2051
            const int r = (d >= 1539) ? 3 : (d >= 1026) ? 2 : (d >= 513) ? 1 : 0;
            const int col = d - 513 * r;
            if (col < PD) {
                vals[k] = inp[gin + d - r];
            } else {
                // positional-embedding channel for row g*4 + r
                const int row = (int)g * 4 + r;
                const int s   = row & (PS - 1);
                const int b   = row >> 12;
                const int len = lengths[b];
                float pe = 0.0f;
                if (s < len) {
                    pe = cosf(((float)s / fmaxf((float)len, 1.0f)) * PI_F);
                }
                vals[k] = pe;
            }
        }
        float4 v;
        v.x = vals[0]; v.y = vals[1]; v.z = vals[2]; v.w = vals[3];
        out[fidx] = v;   // 16B-aligned, dense
    }
}

extern "C" void kernel_launch(void* const* d_in, const int* in_sizes, int n_in,
                              void* d_out, int out_size, void* d_ws, size_t ws_size,
                              hipStream_t stream)
{
    const float* inp     = (const float*)d_in[0];
    const int*   lengths = (const int*)d_in[1];
    float4*      out     = (float4*)d_out;

    // NF4 / (256 threads * 4 iters/thread) = 8208 blocks exactly.
    const int blocks = NF4 / (256 * 4);
    sinpe_kernel<<<blocks, 256, 0, stream>>>(inp, lengths, out);
}

// Round 3
// 231.577 us; speedup vs baseline: 1.0100x; 1.0100x over previous
//
#include <hip/hip_runtime.h>
#include <hip/hip_bf16.h>
#include <math.h>

// inp [B=16, S=4096, D=512] fp32, lengths [16] int32.
// out [B, S, 513] fp32: out[...,0:512] = inp, out[...,512] = pe(b,s).
//
// Strategy: both global sides dense + 16B-aligned; do the 512->513 channel
// shift in LDS.
//   - Block = 256 threads = 8 rows = 16,384 input dwords / 16,416 output dwords.
//   - Phase 1: 4 dense float4 loads/thread (block input base = blk*64 KB,
//     aligned); scatter dwords into LDS image in OUTPUT layout (row*513+col).
//     The misalignment cost lives in LDS (8-way bank conflicts on the b32
//     scatter — ~cycles, fully overlapped with vmem), not in global memory.
//     Threads 0..7 compute the pe channel for the block's 8 rows.
//   - Phase 2: aligned float4 reads from LDS (conflict-free ds_read_b128),
//     dense aligned float4 stores (block out base = blk*16,416 floats; every
//     store 16B-aligned since 16,416 % 4 == 0).
// LDS 16,416 B/block -> 8 blocks/CU -> 32 waves/CU (full occupancy).

#define PB 16
#define PS 4096
#define PD 512
#define ROWS_PER_BLOCK 8
#define IN_DW   (ROWS_PER_BLOCK * PD)        // 4096 dwords in per block
#define OUT_DW  (ROWS_PER_BLOCK * (PD + 1))  // 4104 dwords out per block
#define IN_F4   (IN_DW / 4)                  // 1024
#define OUT_F4  (OUT_DW / 4)                 // 1026
#define NBLOCKS ((PB * PS) / ROWS_PER_BLOCK) // 8192
#define PI_F 3.14159265358979323846f

__global__ __launch_bounds__(256) void sinpe_kernel(
    const float4* __restrict__ in4,
    const int* __restrict__ lengths,
    float4* __restrict__ out4)
{
    __shared__ __align__(16) float lds[OUT_DW];  // 16,416 B

    const int blk = blockIdx.x;   // 0..8191, 8 rows each
    const int t   = threadIdx.x;  // 0..255

    // ---- Phase 1: dense aligned global loads -> LDS in output layout ----
    const float4* __restrict__ in_base = in4 + (size_t)blk * IN_F4;
    #pragma unroll
    for (int j = 0; j < 4; ++j) {
        const int f = j * 256 + t;        // input float4 index within block
        const float4 v = in_base[f];      // dense, 16B-aligned
        const int D = f * 4;              // input dword within block
        const int r = D >> 9;             // local row 0..7
        const int c = D & (PD - 1);       // col 0..508 (never crosses row)
        float* p = &lds[r * (PD + 1) + c];
        p[0] = v.x; p[1] = v.y; p[2] = v.z; p[3] = v.w;
    }

    // pe channel for this block's 8 rows
    if (t < ROWS_PER_BLOCK) {
        const int row = blk * ROWS_PER_BLOCK + t;
        const int s   = row & (PS - 1);
        const int b   = row >> 12;
        const int len = lengths[b];
        float pe = 0.0f;
        if (s < len) {
            pe = cosf(((float)s / fmaxf((float)len, 1.0f)) * PI_F);
        }
        lds[t * (PD + 1) + PD] = pe;
    }

    __syncthreads();

    // ---- Phase 2: aligned LDS float4 reads -> dense aligned global stores ----
    float4* __restrict__ out_base = out4 + (size_t)blk * OUT_F4;
    const float4* __restrict__ lds4 = (const float4*)lds;
    #pragma unroll
    for (int j = 0; j < 5; ++j) {
        const int o = j * 256 + t;        // output float4 within block
        if (o < OUT_F4) {                 // j=4: only t<2 active
            out_base[o] = lds4[o];
        }
    }
}

extern "C" void kernel_launch(void* const* d_in, const int* in_sizes, int n_in,
                              void* d_out, int out_size, void* d_ws, size_t ws_size,
                              hipStream_t stream)
{
    const float4* in4     = (const float4*)d_in[0];
    const int*    lengths = (const int*)d_in[1];
    float4*       out4    = (float4*)d_out;

    sinpe_kernel<<<NBLOCKS, 256, 0, stream>>>(in4, lengths, out4);
}